// Round 5
// baseline (30.729 us; speedup 1.0000x reference)
//
#include <hip/hip_runtime.h>
#include <math.h>

// RDF with Gaussian smearing, N=512 points, 400 bins. Two dispatches:
// K1: NPART blocks histogram unordered pairs into LDS, plain-store partials.
// K2: 1 block reduces partials, normalizes, writes count/bins/rdf.
// out layout: count[0..399], bins[400..800] (401 vals), rdf[801..1200]
#define NBINS 400
#define NPTS  512
#define RMAXF 13.635f
#define BOXF  (2.0f * RMAXF)

template <int NPART>
__global__ __launch_bounds__(256) void rdf_hist(const float* __restrict__ pos,
                                                float* __restrict__ part) {
    __shared__ float hist[NBINS];
    const int tid = threadIdx.x;
    for (int b = tid; b < NBINS; b += 256) hist[b] = 0.0f;
    __syncthreads();

    const float width = RMAXF / 399.0f;            // offsets spacing
    const float inv_w = 399.0f / RMAXF;
    const float coeff = -0.5f * inv_w * inv_w;     // -0.5 / width^2
    const float CUT   = 4.0f;                      // +/-4 sigma (tail ~1.7e-4 rel)

    // Unordered pairs (ordered histogram = 2x this; factor cancels in
    // count/total): slot p -> i = p>>8, k = (p&255)+1, j = (i+k) mod 512.
    // k==256 pairs appear for both endpoints; keep only i<256.
    const int total = NPTS * 256;                  // 131072 slots
    for (int p = blockIdx.x * 256 + tid; p < total; p += NPART * 256) {
        const int i = p >> 8;
        const int k = (p & 255) + 1;
        if (!(k == 256 && i >= 256)) {
            const int j = (i + k) & (NPTS - 1);
            float dx = fabsf(pos[3*i+0] - pos[3*j+0]);
            float dy = fabsf(pos[3*i+1] - pos[3*j+1]);
            float dz = fabsf(pos[3*i+2] - pos[3*j+2]);
            if (dx > RMAXF) dx = BOXF - dx;         // minimum-image fold
            if (dy > RMAXF) dy = BOXF - dy;
            if (dz > RMAXF) dz = BOXF - dz;
            const float dist = sqrtf(dx*dx + dy*dy + dz*dz);
            if (dist > 0.0f) {                      // matches reference self-mask
                const float c = dist * inv_w;       // distance in bin widths
                int b0 = (int)ceilf(c - CUT);
                int b1 = (int)floorf(c + CUT);
                if (b0 < 0) b0 = 0;
                if (b1 > NBINS - 1) b1 = NBINS - 1;
                for (int b = b0; b <= b1; ++b) {
                    const float d = dist - (float)b * width;
                    atomicAdd(&hist[b], __expf(coeff * d * d));
                }
            }
        }
    }
    __syncthreads();
    for (int b = tid; b < NBINS; b += 256)
        part[blockIdx.x * NBINS + b] = hist[b];
}

template <int NPART>
__global__ __launch_bounds__(512) void rdf_final(const float* __restrict__ part,
                                                 float* __restrict__ out) {
    __shared__ float ssum[8];
    const int t = threadIdx.x;

    float v = 0.0f;
    if (t < NBINS) {
        #pragma unroll 16
        for (int p = 0; p < NPART; ++p) v += part[p * NBINS + t];
    }

    // total = sum over bins: wave(64) reduce then cross-wave via LDS
    float s = v;
    #pragma unroll
    for (int o = 32; o > 0; o >>= 1) s += __shfl_down(s, o, 64);
    if ((t & 63) == 0) ssum[t >> 6] = s;
    __syncthreads();
    if (t == 0) {
        float tot = 0.0f;
        #pragma unroll
        for (int w = 0; w < 8; ++w) tot += ssum[w];
        ssum[0] = tot;
    }
    __syncthreads();
    const float tot = ssum[0];

    if (t < NBINS) {
        const float cf = v / tot;
        out[t] = cf;                                   // count (normalized)
        // rdf = cf * V/vol_bin = cf * 400^3 / (3b^2+3b+1) (exact integer form)
        const float denom = (3.0f * t * t + 3.0f * t + 1.0f);
        out[801 + t] = cf * (400.0f * 400.0f * 400.0f) / denom;
    }
    if (t < NBINS + 1) {
        out[NBINS + t] = (float)t * (RMAXF / 400.0f);  // bins = linspace(0, R_MAX, 401)
    }
}

extern "C" void kernel_launch(void* const* d_in, const int* in_sizes, int n_in,
                              void* d_out, int out_size, void* d_ws, size_t ws_size,
                              hipStream_t stream) {
    const float* pos = (const float*)d_in[0];
    float* out = (float*)d_out;
    float* part = (float*)d_ws;   // NPART*NBINS floats, fully overwritten each call

    if (ws_size >= (size_t)512 * NBINS * sizeof(float)) {
        rdf_hist<512><<<512, 256, 0, stream>>>(pos, part);
        rdf_final<512><<<1, 512, 0, stream>>>(part, out);
    } else if (ws_size >= (size_t)256 * NBINS * sizeof(float)) {
        rdf_hist<256><<<256, 256, 0, stream>>>(pos, part);
        rdf_final<256><<<1, 512, 0, stream>>>(part, out);
    } else {
        rdf_hist<128><<<128, 256, 0, stream>>>(pos, part);
        rdf_final<128><<<1, 512, 0, stream>>>(part, out);
    }
}

// Round 6
// 18.794 us; speedup vs baseline: 1.6350x; 1.6350x over previous
//
#include <hip/hip_runtime.h>
#include <math.h>

// RDF with Gaussian smearing, N=512 points, 400 bins. Two dispatches:
// K1: 128 blocks histogram unordered pairs into LDS, plain-store partials.
// K2: 1 block reduces partials, normalizes, writes count/bins/rdf.
// out layout: count[0..399], bins[400..800] (401 vals), rdf[801..1200]
// R6 = exact R4 structure (best: 20.9us), only CUT 5.5 -> 4.0 (one-variable).
#define NBINS 400
#define NPTS  512
#define RMAXF 13.635f
#define BOXF  (2.0f * RMAXF)
#define NPART 128

__global__ __launch_bounds__(256) void rdf_hist(const float* __restrict__ pos,
                                                float* __restrict__ part) {
    __shared__ float hist[NBINS];
    const int tid = threadIdx.x;
    for (int b = tid; b < NBINS; b += 256) hist[b] = 0.0f;
    __syncthreads();

    const float width = RMAXF / 399.0f;            // offsets spacing
    const float inv_w = 399.0f / RMAXF;
    const float coeff = -0.5f * inv_w * inv_w;     // -0.5 / width^2
    const float CUT   = 4.0f;                      // +/-4 sigma (tail ~6e-5 rel)

    // Unordered pairs (ordered histogram = 2x this; factor cancels in
    // count/total): slot p -> i = p>>8, k = (p&255)+1, j = (i+k) mod 512.
    // k==256 pairs appear for both endpoints; keep only i<256.
    const int total = NPTS * 256;                  // 131072 slots
    for (int p = blockIdx.x * 256 + tid; p < total; p += NPART * 256) {
        const int i = p >> 8;
        const int k = (p & 255) + 1;
        if (!(k == 256 && i >= 256)) {
            const int j = (i + k) & (NPTS - 1);
            float dx = fabsf(pos[3*i+0] - pos[3*j+0]);
            float dy = fabsf(pos[3*i+1] - pos[3*j+1]);
            float dz = fabsf(pos[3*i+2] - pos[3*j+2]);
            if (dx > RMAXF) dx = BOXF - dx;         // minimum-image fold
            if (dy > RMAXF) dy = BOXF - dy;
            if (dz > RMAXF) dz = BOXF - dz;
            const float dist = sqrtf(dx*dx + dy*dy + dz*dz);
            if (dist > 0.0f) {                      // matches reference self-mask
                const float c = dist * inv_w;       // distance in bin widths
                int b0 = (int)ceilf(c - CUT);
                int b1 = (int)floorf(c + CUT);
                if (b0 < 0) b0 = 0;
                if (b1 > NBINS - 1) b1 = NBINS - 1;
                for (int b = b0; b <= b1; ++b) {
                    const float d = dist - (float)b * width;
                    atomicAdd(&hist[b], __expf(coeff * d * d));
                }
            }
        }
    }
    __syncthreads();
    for (int b = tid; b < NBINS; b += 256)
        part[blockIdx.x * NBINS + b] = hist[b];
}

__global__ __launch_bounds__(512) void rdf_final(const float* __restrict__ part,
                                                 float* __restrict__ out) {
    __shared__ float ssum[8];
    const int t = threadIdx.x;

    float v = 0.0f;
    if (t < NBINS) {
        #pragma unroll 16
        for (int p = 0; p < NPART; ++p) v += part[p * NBINS + t];
    }

    // total = sum over bins: wave(64) reduce then cross-wave via LDS
    float s = v;
    #pragma unroll
    for (int o = 32; o > 0; o >>= 1) s += __shfl_down(s, o, 64);
    if ((t & 63) == 0) ssum[t >> 6] = s;
    __syncthreads();
    if (t == 0) {
        float tot = 0.0f;
        #pragma unroll
        for (int w = 0; w < 8; ++w) tot += ssum[w];
        ssum[0] = tot;
    }
    __syncthreads();
    const float tot = ssum[0];

    if (t < NBINS) {
        const float cf = v / tot;
        out[t] = cf;                                   // count (normalized)
        // rdf = cf * V/vol_bin = cf * 400^3 / (3b^2+3b+1) (exact integer form)
        const float denom = (3.0f * t * t + 3.0f * t + 1.0f);
        out[801 + t] = cf * (400.0f * 400.0f * 400.0f) / denom;
    }
    if (t < NBINS + 1) {
        out[NBINS + t] = (float)t * (RMAXF / 400.0f);  // bins = linspace(0, R_MAX, 401)
    }
}

extern "C" void kernel_launch(void* const* d_in, const int* in_sizes, int n_in,
                              void* d_out, int out_size, void* d_ws, size_t ws_size,
                              hipStream_t stream) {
    const float* pos = (const float*)d_in[0];
    float* out = (float*)d_out;
    float* part = (float*)d_ws;   // NPART*NBINS floats, fully overwritten each call

    rdf_hist<<<NPART, 256, 0, stream>>>(pos, part);
    rdf_final<<<1, 512, 0, stream>>>(part, out);
}